// Round 13
// baseline (336.308 us; speedup 1.0000x reference)
//
#include <hip/hip_runtime.h>
#include <hip/hip_cooperative_groups.h>
#include <math.h>

#define B 32
#define H 8
#define N 512
#define NBLK 256   // cooperative blocks (1 per CU)
#define TPB 512
#define RPB 64     // G rows per cooperative block
// d_out tail scratch (floats), consumed before k_final overwrites:
#define OFF_PA   8388608             // B*N*8 transposed partials, buffer A
#define OFF_PB   (OFF_PA + 131072)   // buffer B
#define OFF_C0A  (OFF_PB + 131072)   // B*8*8 transposed c0 partials
#define OFF_C0B  (OFF_C0A + 2048)

typedef float f32x4 __attribute__((ext_vector_type(4)));  // ok for nontemporal builtins

// Cross-block data moves through relaxed agent-scope atomics (sc-bit,
// coherence-point accesses). No fences -> no L2 writeback/invalidate storms.
__device__ __forceinline__ float2 atomLoad2(const float* p) {
    unsigned long long u = __hip_atomic_load(
        reinterpret_cast<const unsigned long long*>(p),
        __ATOMIC_RELAXED, __HIP_MEMORY_SCOPE_AGENT);
    union { unsigned long long u; float2 f; } cvt; cvt.u = u;
    return cvt.f;
}
__device__ __forceinline__ void atomStore(float* p, float v) {
    __hip_atomic_store(p, v, __ATOMIC_RELAXED, __HIP_MEMORY_SCOPE_AGENT);
}

// 8-block (one b-group) barrier. __syncthreads() drains vmcnt for every wave,
// so all sc-bit data stores are globally visible before the signal.
__device__ __forceinline__ void group_barrier(int* cnt, int target) {
    __syncthreads();
    if (threadIdx.x == 0) {
        __hip_atomic_fetch_add(cnt, 1, __ATOMIC_RELAXED, __HIP_MEMORY_SCOPE_AGENT);
        while (__hip_atomic_load(cnt, __ATOMIC_RELAXED, __HIP_MEMORY_SCOPE_AGENT) < target)
            __builtin_amdgcn_s_sleep(1);
    }
    __syncthreads();
}

// Zero the group-barrier counters (ws is poisoned 0xAA before timing).
__global__ void k_zero(int* __restrict__ counters) {
    counters[threadIdx.x] = 0;
}

// Fused build + 5x(row,col) normalization. Block (b,g) builds its own 64 G-rows
// directly from its 1 MB input slice into LDS (block-local, no barrier), then
// iterates with fence-free 8-block group barriers. Sum order over h matches the
// old k_build exactly -> bitwise-identical G.
__global__ __launch_bounds__(TPB, 2) void k_coopb(const float* __restrict__ in,
                                                  float* __restrict__ partA,
                                                  float* __restrict__ partB,
                                                  float* __restrict__ c0pA,
                                                  float* __restrict__ c0pB,
                                                  float* __restrict__ rv,
                                                  float* __restrict__ r0v,
                                                  float* __restrict__ cv,
                                                  float* __restrict__ c0v,
                                                  int* __restrict__ counters) {
    __shared__ float Gs[RPB][N];   // 128 KB
    __shared__ float E0g[N];       // exp(x[b, g, 0, :]) (head h=g row-0 slice)
    __shared__ float vec[N];       // c values (row phase)
    __shared__ float EcS[H][RPB];  // exp(x[b, h, rbase+il, 0])
    __shared__ float rloc[RPB];
    __shared__ float c0rec[H];
    __shared__ float r0loc_s;

    const int blk = blockIdx.x;
    const int b = blk >> 3;
    const int g = blk & 7;
    const int rbase = g * RPB;
    const bool owner = (g == 0);
    const int tid = threadIdx.x;
    const int w = tid >> 6, lane = tid & 63;
    int* cnt = counters + b * 16;

    // ---- build phase: G rows straight from input into LDS (16-deep MLP) ----
    const int il4 = tid >> 7;      // 0..3
    const int j4 = tid & 127;      // float4 column index
    const size_t inb = (size_t)b * H * N * N;
    float4 acc[16];
#pragma unroll
    for (int c = 0; c < 16; ++c) acc[c] = make_float4(0.f, 0.f, 0.f, 0.f);
#pragma unroll
    for (int h = 0; h < H; ++h) {
        const float* base = in + inb + (size_t)h * N * N + (size_t)rbase * N;
        float4 xv[16];
#pragma unroll
        for (int c = 0; c < 16; ++c)
            xv[c] = *reinterpret_cast<const float4*>(base + (size_t)(c * 4 + il4) * N + j4 * 4);
#pragma unroll
        for (int c = 0; c < 16; ++c) {
            float4 e;
            e.x = __expf(xv[c].x); e.y = __expf(xv[c].y);
            e.z = __expf(xv[c].z); e.w = __expf(xv[c].w);
            acc[c].x += e.x; acc[c].y += e.y; acc[c].z += e.z; acc[c].w += e.w;
            if (j4 == 0) EcS[h][c * 4 + il4] = e.x;
        }
    }
#pragma unroll
    for (int c = 0; c < 16; ++c)
        *reinterpret_cast<float4*>(&Gs[c * 4 + il4][j4 * 4]) = acc[c];
    if (tid < 128) {   // E0g: exp of row (b, g, 0, :)
        const float4 xr = *reinterpret_cast<const float4*>(in + inb + (size_t)g * N * N + tid * 4);
        E0g[tid * 4 + 0] = __expf(xr.x);
        E0g[tid * 4 + 1] = __expf(xr.y);
        E0g[tid * 4 + 2] = __expf(xr.z);
        E0g[tid * 4 + 3] = __expf(xr.w);
    }
    __syncthreads();
    const float E00g = E0g[0];     // exp(x[b, g, 0, 0])

    for (int it = 0; it < 5; ++it) {
        // ---------- recompute c factors from transposed partials ----------
        if (it == 0) {
            vec[tid] = (tid == 0) ? 0.0f : 1.0f;  // c = 1; j=0 handled via c0 term
            if (tid < H) c0rec[tid] = 1.0f;
        } else {
            const float* pr = (it & 1) ? partB : partA;
            pr += ((size_t)b * N + tid) * 8;
            float cs = 0.0f;
#pragma unroll
            for (int k = 0; k < 4; ++k) {
                float2 d = atomLoad2(pr + 2 * k);
                cs += d.x + d.y;
            }
            vec[tid] = (tid == 0) ? 0.0f : 1.0f / cs;
            if (tid < H) {
                const float* qr = (it & 1) ? c0pB : c0pA;
                qr += (b * 8 + tid) * 8;
                float s = 0.0f;
#pragma unroll
                for (int k = 0; k < 4; ++k) {
                    float2 d = atomLoad2(qr + 2 * k);
                    s += d.x + d.y;
                }
                c0rec[tid] = 1.0f / s;
            }
        }
        __syncthreads();
        float cj[8];
#pragma unroll
        for (int k = 0; k < 8; ++k) cj[k] = vec[lane + 64 * k];
#pragma unroll
        for (int r8 = 0; r8 < 8; ++r8) {
            const int il = w * 8 + r8;
            float pacc = 0.0f;
#pragma unroll
            for (int k = 0; k < 8; ++k) pacc += Gs[il][lane + 64 * k] * cj[k];
#pragma unroll
            for (int s = 32; s > 0; s >>= 1) pacc += __shfl_down(pacc, s, 64);
            if (lane == 0) {
                float s2 = pacc;
#pragma unroll
                for (int h = 0; h < H; ++h) s2 += EcS[h][il] * c0rec[h];
                float rva = 1.0f / s2;
                rloc[il] = rva;                 // garbage for owner il=0, masked below
                if (it == 4) rv[b * N + rbase + il] = rva;
            }
        }
        if (w == g) {   // r0 for head h=g
            float pacc = 0.0f;
#pragma unroll
            for (int k = 0; k < 8; ++k) pacc += E0g[lane + 64 * k] * cj[k];
#pragma unroll
            for (int s = 32; s > 0; s >>= 1) pacc += __shfl_down(pacc, s, 64);
            if (lane == 0) {
                float v = 1.0f / (pacc + E00g * c0rec[g]);
                r0loc_s = v;
                if (it == 4) r0v[b * H + g] = v;
            }
        }
        __syncthreads();
        // ---------- col phase: partial column sums (transposed store) ----------
        {
            float* pw = ((it + 1) & 1) ? partB : partA;
            float* qw = ((it + 1) & 1) ? c0pB : c0pA;
            const float r0l = r0loc_s;
            float acc2 = 0.0f;
            const int il0 = owner ? 1 : 0;  // global row 0 handled via E0 terms
#pragma unroll 8
            for (int il = il0; il < RPB; ++il) acc2 += Gs[il][tid] * rloc[il];
            acc2 += E0g[tid] * r0l;         // head g's i=0 contribution
            atomStore(&pw[((size_t)b * N + tid) * 8 + g], acc2);
            float q = EcS[w][lane] * ((owner && lane == 0) ? 0.0f : rloc[lane]);
            if (w == g && lane == 0) q += E00g * r0l;
#pragma unroll
            for (int s = 32; s > 0; s >>= 1) q += __shfl_down(q, s, 64);
            if (lane == 0) atomStore(&qw[(b * 8 + w) * 8 + g], q);
        }
        group_barrier(cnt, (it + 1) * 8);
    }
    // ---- finalize c factors (block g==0 of each b) ----
    if (owner) {
        const float* pr = partB + ((size_t)b * N + tid) * 8;   // (4+1)&1 == 1
        float cs = 0.0f;
#pragma unroll
        for (int k = 0; k < 4; ++k) {
            float2 d = atomLoad2(pr + 2 * k);
            cs += d.x + d.y;
        }
        cv[b * N + tid] = (tid == 0) ? 1.0f : 1.0f / cs;
        if (tid < H) {
            const float* qr = c0pB + (b * 8 + tid) * 8;
            float s = 0.0f;
#pragma unroll
            for (int k = 0; k < 4; ++k) {
                float2 d = atomLoad2(qr + 2 * k);
                s += d.x + d.y;
            }
            c0v[b * H + tid] = 1.0f / s;
        }
    }
}

// 8 independent float4s per thread. CACHED input loads (harvest L3 residency left
// by the fused build's read); non-temporal stores (no-allocate, keep input resident).
__global__ __launch_bounds__(256) void k_final(const float* __restrict__ in,
                                               const float* __restrict__ rv,
                                               const float* __restrict__ r0v,
                                               const float* __restrict__ cv,
                                               const float* __restrict__ c0v,
                                               float* __restrict__ out) {
    const size_t v0 = (size_t)blockIdx.x * 2048 + threadIdx.x;
    float4 x[8];
#pragma unroll
    for (int s = 0; s < 8; ++s)
        x[s] = reinterpret_cast<const float4*>(in)[v0 + (size_t)s * 256];
#pragma unroll
    for (int s = 0; s < 8; ++s) {
        const size_t v = v0 + (size_t)s * 256;   // float4 index
        const int j4 = (int)(v & 127);
        size_t rest = v >> 7;
        const int i = (int)(rest & 511); rest >>= 9;
        const int h = (int)(rest & 7);
        const int b = (int)(rest >> 3);
        const float R = (i == 0) ? r0v[b * H + h] : rv[b * N + i];
        float4 cl = reinterpret_cast<const float4*>(cv + b * N)[j4];
        if (j4 == 0) cl.x = c0v[b * H + h];
        f32x4 o;
        o.x = __expf(x[s].x) * R * cl.x;
        o.y = __expf(x[s].y) * R * cl.y;
        o.z = __expf(x[s].z) * R * cl.z;
        o.w = __expf(x[s].w) * R * cl.w;
        __builtin_nontemporal_store(o, reinterpret_cast<f32x4*>(out) + v);
    }
}

extern "C" void kernel_launch(void* const* d_in, const int* in_sizes, int n_in,
                              void* d_out, int out_size, void* d_ws, size_t ws_size,
                              hipStream_t stream) {
    (void)in_sizes; (void)n_in; (void)out_size; (void)ws_size;
    const float* in = (const float*)d_in[0];
    float* out = (float*)d_out;
    float* ws = (float*)d_ws;

    // persistent factor vectors (must survive into k_final) live in ws
    float* rv  = ws;           // B*N
    float* cv  = ws + 16384;   // B*N
    float* r0v = ws + 32768;   // B*H
    float* c0v = ws + 33024;   // B*H
    int* counters = (int*)(ws + 33280);  // 32 groups x 16 ints

    // partial buffers live in the tail of d_out (consumed before k_final writes)
    float* pA  = out + OFF_PA;    // B*N*8 (transposed)
    float* pB  = out + OFF_PB;    // B*N*8
    float* c0A = out + OFF_C0A;   // B*8*8
    float* c0B = out + OFF_C0B;   // B*8*8

    k_zero<<<1, 512, 0, stream>>>(counters);

    void* args[] = {(void*)&in, (void*)&pA, (void*)&pB, (void*)&c0A, (void*)&c0B,
                    (void*)&rv, (void*)&r0v, (void*)&cv, (void*)&c0v, (void*)&counters};
    hipLaunchCooperativeKernel(reinterpret_cast<void*>(k_coopb), dim3(NBLK), dim3(TPB),
                               args, 0, stream);

    k_final<<<8192, 256, 0, stream>>>(in, rv, r0v, cv, c0v, out);
}

// Round 14
// 197.700 us; speedup vs baseline: 1.7011x; 1.7011x over previous
//
#include <hip/hip_runtime.h>
#include <hip/hip_cooperative_groups.h>
#include <math.h>

#define B 32
#define H 8
#define N 512
#define NBLK 256   // cooperative blocks (1 per CU)
#define TPB 512
#define RPB 64     // G rows per cooperative block
// d_out tail scratch layout (floats):
#define OFF_E0   8388608           // B*N*N
#define OFF_EC   (OFF_E0 + 131072)
#define OFF_PA   (OFF_EC + 131072)   // B*N*8 transposed partials, buffer A
#define OFF_PB   (OFF_PA + 131072)   // buffer B
#define OFF_C0A  (OFF_PB + 131072)   // B*8*8 transposed c0 partials
#define OFF_C0B  (OFF_C0A + 2048)

typedef float f32x4 __attribute__((ext_vector_type(4)));  // ok for nontemporal builtins

// All cross-block data moves through relaxed agent-scope atomics (sc-bit,
// coherence-point accesses). No fences anywhere -> no L2 writeback/invalidate.
__device__ __forceinline__ float atomLoad(const float* p) {
    return __hip_atomic_load(p, __ATOMIC_RELAXED, __HIP_MEMORY_SCOPE_AGENT);
}
// 64-bit coherent load of two adjacent floats (global_load_dwordx2 + sc bits)
__device__ __forceinline__ float2 atomLoad2(const float* p) {
    unsigned long long u = __hip_atomic_load(
        reinterpret_cast<const unsigned long long*>(p),
        __ATOMIC_RELAXED, __HIP_MEMORY_SCOPE_AGENT);
    union { unsigned long long u; float2 f; } cvt; cvt.u = u;
    return cvt.f;
}
__device__ __forceinline__ void atomStore(float* p, float v) {
    __hip_atomic_store(p, v, __ATOMIC_RELAXED, __HIP_MEMORY_SCOPE_AGENT);
}

// 8-block (one b-group) barrier. __syncthreads() drains vmcnt for every wave,
// so all sc-bit data stores are globally visible before the signal.
__device__ __forceinline__ void group_barrier(int* cnt, int target) {
    __syncthreads();
    if (threadIdx.x == 0) {
        __hip_atomic_fetch_add(cnt, 1, __ATOMIC_RELAXED, __HIP_MEMORY_SCOPE_AGENT);
        while (__hip_atomic_load(cnt, __ATOMIC_RELAXED, __HIP_MEMORY_SCOPE_AGENT) < target)
            __builtin_amdgcn_s_sleep(1);
    }
    __syncthreads();
}

// Build G[b,i,j] = sum_h exp(x); E0[b,h,j] = exp(x[b,h,0,j]); Ec[b,h,i] = exp(x[b,h,i,0]).
// Cached loads on purpose: input should stay L3-resident for k_final's re-read.
// Also zeroes the group-barrier counters (completes before k_coop launches).
__global__ __launch_bounds__(128) void k_build(const float* __restrict__ in,
                                               float* __restrict__ G,
                                               float* __restrict__ E0,
                                               float* __restrict__ Ec,
                                               int* __restrict__ counters) {
    const int i = blockIdx.x;
    const int b = blockIdx.y;
    const int t = threadIdx.x;          // float4 column index, 0..127
    if (i == 0 && b == 0) {
#pragma unroll
        for (int k = 0; k < 4; ++k) counters[k * 128 + t] = 0;
    }
    const size_t inb = (size_t)b * H * N * N;
    float4 acc = make_float4(0.f, 0.f, 0.f, 0.f);
#pragma unroll
    for (int h = 0; h < H; ++h) {
        const float4 x = *reinterpret_cast<const float4*>(
            in + inb + ((size_t)h * N + i) * N + t * 4);
        float4 e;
        e.x = __expf(x.x); e.y = __expf(x.y); e.z = __expf(x.z); e.w = __expf(x.w);
        acc.x += e.x; acc.y += e.y; acc.z += e.z; acc.w += e.w;
        if (t == 0) Ec[(b * H + h) * N + i] = e.x;
        if (i == 0) *reinterpret_cast<float4*>(E0 + (b * H + h) * N + t * 4) = e;
    }
    *reinterpret_cast<float4*>(G + ((size_t)b * N + i) * N + t * 4) = acc;
}

// 5 x (row-normalize, col-normalize) with G LDS-resident; fence-free 8-block barriers.
// Partials are stored TRANSPOSED: pT[b][j][8] (writer g -> slot [j][g]) so readers
// re-reduce with four 64-bit coherent loads instead of 16 scalar ones.
__global__ __launch_bounds__(TPB) void k_coop(const float* __restrict__ G,
                                              const float* __restrict__ E0,
                                              const float* __restrict__ Ec,
                                              float* __restrict__ partA,
                                              float* __restrict__ partB,
                                              float* __restrict__ c0pA,
                                              float* __restrict__ c0pB,
                                              float* __restrict__ rv,
                                              float* __restrict__ r0v,
                                              float* __restrict__ cv,
                                              float* __restrict__ c0v,
                                              int* __restrict__ counters) {
    __shared__ float Gs[RPB][N];   // 128 KB
    __shared__ float E0g[N];       // this block's head (h=g) row-0 slice
    __shared__ float vec[N];       // c values (row phase)
    __shared__ float EcS[H][RPB];  // Ec for owned rows
    __shared__ float rloc[RPB];
    __shared__ float c0rec[H];
    __shared__ float r0loc_s;

    const int blk = blockIdx.x;
    const int b = blk >> 3;
    const int g = blk & 7;
    const int rbase = g * RPB;
    const bool owner = (g == 0);
    const int tid = threadIdx.x;
    const int w = tid >> 6, lane = tid & 63;
    int* cnt = counters + b * 16;

    // ---- async stage G into LDS (wave-linear layout matches global_load_lds) ----
    {
        const float4* Gg = reinterpret_cast<const float4*>(G + ((size_t)(b * N) + rbase) * N);
        float4* Gl = reinterpret_cast<float4*>(&Gs[0][0]);
#pragma unroll
        for (int k = 0; k < RPB * N / 4 / TPB; ++k) {
            const int t = k * TPB + tid;
            __builtin_amdgcn_global_load_lds(
                (const __attribute__((address_space(1))) void*)(Gg + t),
                (__attribute__((address_space(3))) void*)(Gl + t),
                16, 0, 0);
        }
    }
    EcS[tid >> 6][tid & 63] = Ec[(b * H + (tid >> 6)) * N + rbase + (tid & 63)];
    E0g[tid] = E0[(b * H + g) * N + tid];
    const float E00g = Ec[(b * H + g) * N];  // E[b,g,0,0]
    __syncthreads();

    for (int it = 0; it < 5; ++it) {
        // ---------- recompute c factors from transposed partials ----------
        if (it == 0) {
            vec[tid] = (tid == 0) ? 0.0f : 1.0f;  // c = 1; j=0 handled via c0 term
            if (tid < H) c0rec[tid] = 1.0f;
        } else {
            const float* pr = (it & 1) ? partB : partA;
            pr += ((size_t)b * N + tid) * 8;
            float cs = 0.0f;
#pragma unroll
            for (int k = 0; k < 4; ++k) {
                float2 d = atomLoad2(pr + 2 * k);
                cs += d.x + d.y;
            }
            vec[tid] = (tid == 0) ? 0.0f : 1.0f / cs;
            if (tid < H) {
                const float* qr = (it & 1) ? c0pB : c0pA;
                qr += (b * 8 + tid) * 8;
                float s = 0.0f;
#pragma unroll
                for (int k = 0; k < 4; ++k) {
                    float2 d = atomLoad2(qr + 2 * k);
                    s += d.x + d.y;
                }
                c0rec[tid] = 1.0f / s;
            }
        }
        __syncthreads();
        float cj[8];
#pragma unroll
        for (int k = 0; k < 8; ++k) cj[k] = vec[lane + 64 * k];
#pragma unroll
        for (int r8 = 0; r8 < 8; ++r8) {
            const int il = w * 8 + r8;
            float pacc = 0.0f;
#pragma unroll
            for (int k = 0; k < 8; ++k) pacc += Gs[il][lane + 64 * k] * cj[k];
#pragma unroll
            for (int s = 32; s > 0; s >>= 1) pacc += __shfl_down(pacc, s, 64);
            if (lane == 0) {
                float s2 = pacc;
#pragma unroll
                for (int h = 0; h < H; ++h) s2 += EcS[h][il] * c0rec[h];
                float rva = 1.0f / s2;
                rloc[il] = rva;                 // garbage for owner il=0, masked below
                if (it == 4) rv[b * N + rbase + il] = rva;
            }
        }
        if (w == g) {   // r0 for head h=g
            float pacc = 0.0f;
#pragma unroll
            for (int k = 0; k < 8; ++k) pacc += E0g[lane + 64 * k] * cj[k];
#pragma unroll
            for (int s = 32; s > 0; s >>= 1) pacc += __shfl_down(pacc, s, 64);
            if (lane == 0) {
                float v = 1.0f / (pacc + E00g * c0rec[g]);
                r0loc_s = v;
                if (it == 4) r0v[b * H + g] = v;
            }
        }
        __syncthreads();
        // ---------- col phase: partial column sums (transposed store) ----------
        {
            float* pw = ((it + 1) & 1) ? partB : partA;
            float* qw = ((it + 1) & 1) ? c0pB : c0pA;
            const float r0l = r0loc_s;
            float acc = 0.0f;
            const int il0 = owner ? 1 : 0;  // global row 0 handled via E0 terms
#pragma unroll 8
            for (int il = il0; il < RPB; ++il) acc += Gs[il][tid] * rloc[il];
            acc += E0g[tid] * r0l;          // head g's i=0 contribution
            atomStore(&pw[((size_t)b * N + tid) * 8 + g], acc);
            float q = EcS[w][lane] * ((owner && lane == 0) ? 0.0f : rloc[lane]);
            if (w == g && lane == 0) q += E00g * r0l;
#pragma unroll
            for (int s = 32; s > 0; s >>= 1) q += __shfl_down(q, s, 64);
            if (lane == 0) atomStore(&qw[(b * 8 + w) * 8 + g], q);
        }
        group_barrier(cnt, (it + 1) * 8);
    }
    // ---- finalize c factors (block g==0 of each b) ----
    if (owner) {
        const float* pr = partB + ((size_t)b * N + tid) * 8;   // (4+1)&1 == 1
        float cs = 0.0f;
#pragma unroll
        for (int k = 0; k < 4; ++k) {
            float2 d = atomLoad2(pr + 2 * k);
            cs += d.x + d.y;
        }
        cv[b * N + tid] = (tid == 0) ? 1.0f : 1.0f / cs;
        if (tid < H) {
            const float* qr = c0pB + (b * 8 + tid) * 8;
            float s = 0.0f;
#pragma unroll
            for (int k = 0; k < 4; ++k) {
                float2 d = atomLoad2(qr + 2 * k);
                s += d.x + d.y;
            }
            c0v[b * H + tid] = 1.0f / s;
        }
    }
}

// 8 independent float4s per thread. CACHED input loads (harvest L3 residency left
// by k_build's read); non-temporal stores only (write-streaming, don't displace).
__global__ __launch_bounds__(256) void k_final(const float* __restrict__ in,
                                               const float* __restrict__ rv,
                                               const float* __restrict__ r0v,
                                               const float* __restrict__ cv,
                                               const float* __restrict__ c0v,
                                               float* __restrict__ out) {
    const size_t v0 = (size_t)blockIdx.x * 2048 + threadIdx.x;
    float4 x[8];
#pragma unroll
    for (int s = 0; s < 8; ++s)
        x[s] = reinterpret_cast<const float4*>(in)[v0 + (size_t)s * 256];
#pragma unroll
    for (int s = 0; s < 8; ++s) {
        const size_t v = v0 + (size_t)s * 256;   // float4 index
        const int j4 = (int)(v & 127);
        size_t rest = v >> 7;
        const int i = (int)(rest & 511); rest >>= 9;
        const int h = (int)(rest & 7);
        const int b = (int)(rest >> 3);
        const float R = (i == 0) ? r0v[b * H + h] : rv[b * N + i];
        float4 cl = reinterpret_cast<const float4*>(cv + b * N)[j4];
        if (j4 == 0) cl.x = c0v[b * H + h];
        f32x4 o;
        o.x = __expf(x[s].x) * R * cl.x;
        o.y = __expf(x[s].y) * R * cl.y;
        o.z = __expf(x[s].z) * R * cl.z;
        o.w = __expf(x[s].w) * R * cl.w;
        __builtin_nontemporal_store(o, reinterpret_cast<f32x4*>(out) + v);
    }
}

extern "C" void kernel_launch(void* const* d_in, const int* in_sizes, int n_in,
                              void* d_out, int out_size, void* d_ws, size_t ws_size,
                              hipStream_t stream) {
    (void)in_sizes; (void)n_in; (void)out_size; (void)ws_size;
    const float* in = (const float*)d_in[0];
    float* out = (float*)d_out;
    float* ws = (float*)d_ws;

    // persistent factor vectors (must survive into k_final) live in ws
    float* rv  = ws;           // B*N
    float* cv  = ws + 16384;   // B*N
    float* r0v = ws + 32768;   // B*H
    float* c0v = ws + 33024;   // B*H
    int* counters = (int*)(ws + 33280);  // 32 groups x 16 ints

    // pre-final scratch lives in the tail of d_out (fully consumed before k_final writes)
    float* G   = out;             // B*N*N
    float* E0  = out + OFF_E0;    // B*H*N
    float* Ec  = out + OFF_EC;    // B*H*N
    float* pA  = out + OFF_PA;    // B*N*8 (transposed)
    float* pB  = out + OFF_PB;    // B*N*8
    float* c0A = out + OFF_C0A;   // B*8*8
    float* c0B = out + OFF_C0B;   // B*8*8

    k_build<<<dim3(N, B), 128, 0, stream>>>(in, G, E0, Ec, counters);

    void* args[] = {(void*)&G, (void*)&E0, (void*)&Ec, (void*)&pA, (void*)&pB,
                    (void*)&c0A, (void*)&c0B, (void*)&rv, (void*)&r0v,
                    (void*)&cv, (void*)&c0v, (void*)&counters};
    hipLaunchCooperativeKernel(reinterpret_cast<void*>(k_coop), dim3(NBLK), dim3(TPB),
                               args, 0, stream);

    k_final<<<8192, 256, 0, stream>>>(in, rv, r0v, cv, c0v, out);
}

// Round 15
// 182.478 us; speedup vs baseline: 1.8430x; 1.0834x over previous
//
#include <hip/hip_runtime.h>
#include <hip/hip_cooperative_groups.h>
#include <math.h>

#define B 32
#define H 8
#define N 512
#define NBLK 256   // cooperative blocks (1 per CU)
#define TPB 512
#define RPB 64     // G rows per cooperative block
// d_out tail scratch (floats), consumed before k_final overwrites:
#define OFF_PA   8388608             // B*N*8 transposed partials, buffer A
#define OFF_PB   (OFF_PA + 131072)   // buffer B
#define OFF_C0A  (OFF_PB + 131072)   // B*8*8 transposed c0 partials
#define OFF_C0B  (OFF_C0A + 2048)

typedef float f32x4 __attribute__((ext_vector_type(4)));  // ok for nontemporal builtins

// Cross-block data moves through relaxed agent-scope atomics (sc-bit,
// coherence-point accesses). No fences -> no L2 writeback/invalidate storms.
__device__ __forceinline__ float2 atomLoad2(const float* p) {
    unsigned long long u = __hip_atomic_load(
        reinterpret_cast<const unsigned long long*>(p),
        __ATOMIC_RELAXED, __HIP_MEMORY_SCOPE_AGENT);
    union { unsigned long long u; float2 f; } cvt; cvt.u = u;
    return cvt.f;
}
__device__ __forceinline__ void atomStore(float* p, float v) {
    __hip_atomic_store(p, v, __ATOMIC_RELAXED, __HIP_MEMORY_SCOPE_AGENT);
}

// 8-block (one b-group) barrier. __syncthreads() drains vmcnt for every wave,
// so all sc-bit data stores are globally visible before the signal.
__device__ __forceinline__ void group_barrier(int* cnt, int target) {
    __syncthreads();
    if (threadIdx.x == 0) {
        __hip_atomic_fetch_add(cnt, 1, __ATOMIC_RELAXED, __HIP_MEMORY_SCOPE_AGENT);
        while (__hip_atomic_load(cnt, __ATOMIC_RELAXED, __HIP_MEMORY_SCOPE_AGENT) < target)
            __builtin_amdgcn_s_sleep(1);
    }
    __syncthreads();
}

// Zero the group-barrier counters (ws is poisoned 0xAA before timing).
__global__ void k_zero(int* __restrict__ counters) {
    counters[threadIdx.x] = 0;
}

// Fused build + 5x(row,col) normalization. Block (b,g) builds its own 64 G-rows
// directly from its 1 MB input slice into LDS — REGISTER-LEAN: 16 sequential
// chunks, each with only xv[8]+acc live (~50 VGPR, no spill; round-13 had
// acc[16]+xv[16]=128 VGPR -> 238 MB scratch spill). Sum order over h matches
// the old k_build exactly -> bitwise-identical G.
__global__ __launch_bounds__(TPB) void k_coopb(const float* __restrict__ in,
                                               float* __restrict__ partA,
                                               float* __restrict__ partB,
                                               float* __restrict__ c0pA,
                                               float* __restrict__ c0pB,
                                               float* __restrict__ rv,
                                               float* __restrict__ r0v,
                                               float* __restrict__ cv,
                                               float* __restrict__ c0v,
                                               int* __restrict__ counters) {
    __shared__ float Gs[RPB][N];   // 128 KB
    __shared__ float E0g[N];       // exp(x[b, g, 0, :]) (head h=g row-0 slice)
    __shared__ float vec[N];       // c values (row phase)
    __shared__ float EcS[H][RPB];  // exp(x[b, h, rbase+il, 0])
    __shared__ float rloc[RPB];
    __shared__ float c0rec[H];
    __shared__ float r0loc_s;

    const int blk = blockIdx.x;
    const int b = blk >> 3;
    const int g = blk & 7;
    const int rbase = g * RPB;
    const bool owner = (g == 0);
    const int tid = threadIdx.x;
    const int w = tid >> 6, lane = tid & 63;
    int* cnt = counters + b * 16;

    // ---- build phase: G rows straight from input into LDS (8-deep MLP/chunk) ----
    const int il4 = tid >> 7;      // 0..3
    const int j4 = tid & 127;      // float4 column index
    const size_t inb = (size_t)b * H * N * N;
    for (int c = 0; c < 16; ++c) {
        const int il = c * 4 + il4;
        const float* rowbase = in + inb + (size_t)(rbase + il) * N + j4 * 4;
        float4 xv[8];
#pragma unroll
        for (int h = 0; h < H; ++h)
            xv[h] = *reinterpret_cast<const float4*>(rowbase + (size_t)h * N * N);
        float4 acc = make_float4(0.f, 0.f, 0.f, 0.f);
#pragma unroll
        for (int h = 0; h < H; ++h) {
            float4 e;
            e.x = __expf(xv[h].x); e.y = __expf(xv[h].y);
            e.z = __expf(xv[h].z); e.w = __expf(xv[h].w);
            acc.x += e.x; acc.y += e.y; acc.z += e.z; acc.w += e.w;
            if (j4 == 0) EcS[h][il] = e.x;
        }
        *reinterpret_cast<float4*>(&Gs[il][j4 * 4]) = acc;
    }
    if (tid < 128) {   // E0g: exp of row (b, g, 0, :)
        const float4 xr = *reinterpret_cast<const float4*>(in + inb + (size_t)g * N * N + tid * 4);
        E0g[tid * 4 + 0] = __expf(xr.x);
        E0g[tid * 4 + 1] = __expf(xr.y);
        E0g[tid * 4 + 2] = __expf(xr.z);
        E0g[tid * 4 + 3] = __expf(xr.w);
    }
    __syncthreads();
    const float E00g = E0g[0];     // exp(x[b, g, 0, 0])

    for (int it = 0; it < 5; ++it) {
        // ---------- recompute c factors from transposed partials ----------
        if (it == 0) {
            vec[tid] = (tid == 0) ? 0.0f : 1.0f;  // c = 1; j=0 handled via c0 term
            if (tid < H) c0rec[tid] = 1.0f;
        } else {
            const float* pr = (it & 1) ? partB : partA;
            pr += ((size_t)b * N + tid) * 8;
            float cs = 0.0f;
#pragma unroll
            for (int k = 0; k < 4; ++k) {
                float2 d = atomLoad2(pr + 2 * k);
                cs += d.x + d.y;
            }
            vec[tid] = (tid == 0) ? 0.0f : 1.0f / cs;
            if (tid < H) {
                const float* qr = (it & 1) ? c0pB : c0pA;
                qr += (b * 8 + tid) * 8;
                float s = 0.0f;
#pragma unroll
                for (int k = 0; k < 4; ++k) {
                    float2 d = atomLoad2(qr + 2 * k);
                    s += d.x + d.y;
                }
                c0rec[tid] = 1.0f / s;
            }
        }
        __syncthreads();
        float cj[8];
#pragma unroll
        for (int k = 0; k < 8; ++k) cj[k] = vec[lane + 64 * k];
#pragma unroll
        for (int r8 = 0; r8 < 8; ++r8) {
            const int il = w * 8 + r8;
            float pacc = 0.0f;
#pragma unroll
            for (int k = 0; k < 8; ++k) pacc += Gs[il][lane + 64 * k] * cj[k];
#pragma unroll
            for (int s = 32; s > 0; s >>= 1) pacc += __shfl_down(pacc, s, 64);
            if (lane == 0) {
                float s2 = pacc;
#pragma unroll
                for (int h = 0; h < H; ++h) s2 += EcS[h][il] * c0rec[h];
                float rva = 1.0f / s2;
                rloc[il] = rva;                 // garbage for owner il=0, masked below
                if (it == 4) rv[b * N + rbase + il] = rva;
            }
        }
        if (w == g) {   // r0 for head h=g
            float pacc = 0.0f;
#pragma unroll
            for (int k = 0; k < 8; ++k) pacc += E0g[lane + 64 * k] * cj[k];
#pragma unroll
            for (int s = 32; s > 0; s >>= 1) pacc += __shfl_down(pacc, s, 64);
            if (lane == 0) {
                float v = 1.0f / (pacc + E00g * c0rec[g]);
                r0loc_s = v;
                if (it == 4) r0v[b * H + g] = v;
            }
        }
        __syncthreads();
        // ---------- col phase: partial column sums (transposed store) ----------
        {
            float* pw = ((it + 1) & 1) ? partB : partA;
            float* qw = ((it + 1) & 1) ? c0pB : c0pA;
            const float r0l = r0loc_s;
            float acc2 = 0.0f;
            const int il0 = owner ? 1 : 0;  // global row 0 handled via E0 terms
#pragma unroll 8
            for (int il = il0; il < RPB; ++il) acc2 += Gs[il][tid] * rloc[il];
            acc2 += E0g[tid] * r0l;         // head g's i=0 contribution
            atomStore(&pw[((size_t)b * N + tid) * 8 + g], acc2);
            float q = EcS[w][lane] * ((owner && lane == 0) ? 0.0f : rloc[lane]);
            if (w == g && lane == 0) q += E00g * r0l;
#pragma unroll
            for (int s = 32; s > 0; s >>= 1) q += __shfl_down(q, s, 64);
            if (lane == 0) atomStore(&qw[(b * 8 + w) * 8 + g], q);
        }
        group_barrier(cnt, (it + 1) * 8);
    }
    // ---- finalize c factors (block g==0 of each b) ----
    if (owner) {
        const float* pr = partB + ((size_t)b * N + tid) * 8;   // (4+1)&1 == 1
        float cs = 0.0f;
#pragma unroll
        for (int k = 0; k < 4; ++k) {
            float2 d = atomLoad2(pr + 2 * k);
            cs += d.x + d.y;
        }
        cv[b * N + tid] = (tid == 0) ? 1.0f : 1.0f / cs;
        if (tid < H) {
            const float* qr = c0pB + (b * 8 + tid) * 8;
            float s = 0.0f;
#pragma unroll
            for (int k = 0; k < 4; ++k) {
                float2 d = atomLoad2(qr + 2 * k);
                s += d.x + d.y;
            }
            c0v[b * H + tid] = 1.0f / s;
        }
    }
}

// 8 independent float4s per thread. CACHED input loads (harvest L3 residency left
// by the fused build's read); non-temporal stores (no-allocate, keep input resident).
__global__ __launch_bounds__(256) void k_final(const float* __restrict__ in,
                                               const float* __restrict__ rv,
                                               const float* __restrict__ r0v,
                                               const float* __restrict__ cv,
                                               const float* __restrict__ c0v,
                                               float* __restrict__ out) {
    const size_t v0 = (size_t)blockIdx.x * 2048 + threadIdx.x;
    float4 x[8];
#pragma unroll
    for (int s = 0; s < 8; ++s)
        x[s] = reinterpret_cast<const float4*>(in)[v0 + (size_t)s * 256];
#pragma unroll
    for (int s = 0; s < 8; ++s) {
        const size_t v = v0 + (size_t)s * 256;   // float4 index
        const int j4 = (int)(v & 127);
        size_t rest = v >> 7;
        const int i = (int)(rest & 511); rest >>= 9;
        const int h = (int)(rest & 7);
        const int b = (int)(rest >> 3);
        const float R = (i == 0) ? r0v[b * H + h] : rv[b * N + i];
        float4 cl = reinterpret_cast<const float4*>(cv + b * N)[j4];
        if (j4 == 0) cl.x = c0v[b * H + h];
        f32x4 o;
        o.x = __expf(x[s].x) * R * cl.x;
        o.y = __expf(x[s].y) * R * cl.y;
        o.z = __expf(x[s].z) * R * cl.z;
        o.w = __expf(x[s].w) * R * cl.w;
        __builtin_nontemporal_store(o, reinterpret_cast<f32x4*>(out) + v);
    }
}

extern "C" void kernel_launch(void* const* d_in, const int* in_sizes, int n_in,
                              void* d_out, int out_size, void* d_ws, size_t ws_size,
                              hipStream_t stream) {
    (void)in_sizes; (void)n_in; (void)out_size; (void)ws_size;
    const float* in = (const float*)d_in[0];
    float* out = (float*)d_out;
    float* ws = (float*)d_ws;

    // persistent factor vectors (must survive into k_final) live in ws
    float* rv  = ws;           // B*N
    float* cv  = ws + 16384;   // B*N
    float* r0v = ws + 32768;   // B*H
    float* c0v = ws + 33024;   // B*H
    int* counters = (int*)(ws + 33280);  // 32 groups x 16 ints

    // partial buffers live in the tail of d_out (consumed before k_final writes)
    float* pA  = out + OFF_PA;    // B*N*8 (transposed)
    float* pB  = out + OFF_PB;    // B*N*8
    float* c0A = out + OFF_C0A;   // B*8*8
    float* c0B = out + OFF_C0B;   // B*8*8

    k_zero<<<1, 512, 0, stream>>>(counters);

    void* args[] = {(void*)&in, (void*)&pA, (void*)&pB, (void*)&c0A, (void*)&c0B,
                    (void*)&rv, (void*)&r0v, (void*)&cv, (void*)&c0v, (void*)&counters};
    hipLaunchCooperativeKernel(reinterpret_cast<void*>(k_coopb), dim3(NBLK), dim3(TPB),
                               args, 0, stream);

    k_final<<<8192, 256, 0, stream>>>(in, rv, r0v, cv, c0v, out);
}